// Round 1
// baseline (781.055 us; speedup 1.0000x reference)
//
#include <hip/hip_runtime.h>

// ---------------------------------------------------------------------------
// 3-layer GCN: out = ReLU(Â(ReLU(Â(Â (X W1^T) +b1) W2^T +b2)) W3^T) +b3
// Â = D^{-1/2}(A+I)D^{-1/2}, deg = in-degree + 1 (self loop).
// Strategy: xs = dinv[m] * (X @ W^T)  (fused in GEMM epilogue)
//           agg[d] = sum_{edges s->d} xs[s] + xs[d]
//           out[d] = dinv[d]*agg[d] + b  (+ReLU)   (fused in agg epilogue)
// ---------------------------------------------------------------------------

__global__ __launch_bounds__(256) void count_deg(const int* __restrict__ dst,
                                                 int* __restrict__ cnt, int E) {
  int e = blockIdx.x * 256 + threadIdx.x;
  if (e < E) atomicAdd(&cnt[dst[e]], 1);
}

__global__ __launch_bounds__(256) void make_dinv(const int* __restrict__ cnt,
                                                 float* __restrict__ dinv, int N) {
  int i = blockIdx.x * 256 + threadIdx.x;
  if (i < N) dinv[i] = rsqrtf((float)(cnt[i] + 1));  // deg >= 1 always
}

// per-block exclusive scan (Hillis-Steele) of cnt -> off, block totals -> bsum
__global__ __launch_bounds__(256) void scan_block(const int* __restrict__ cnt,
                                                  int* __restrict__ off,
                                                  int* __restrict__ bsum, int N) {
  __shared__ int s[256];
  int t = threadIdx.x;
  int i = blockIdx.x * 256 + t;
  int v = (i < N) ? cnt[i] : 0;
  s[t] = v;
  __syncthreads();
  for (int d = 1; d < 256; d <<= 1) {
    int add = (t >= d) ? s[t - d] : 0;
    __syncthreads();
    s[t] += add;
    __syncthreads();
  }
  if (i < N) off[i] = s[t] - v;  // exclusive within block
  if (t == 255) bsum[blockIdx.x] = s[255];
}

__global__ __launch_bounds__(512) void scan_top(const int* __restrict__ bsum,
                                                int* __restrict__ bbase, int nb) {
  __shared__ int s[512];
  int t = threadIdx.x;
  int v = (t < nb) ? bsum[t] : 0;
  s[t] = v;
  __syncthreads();
  for (int d = 1; d < 512; d <<= 1) {
    int add = (t >= d) ? s[t - d] : 0;
    __syncthreads();
    s[t] += add;
    __syncthreads();
  }
  if (t < nb) bbase[t] = s[t] - v;
}

__global__ __launch_bounds__(256) void scan_add(int* __restrict__ off,
                                                const int* __restrict__ bbase,
                                                int N, int E) {
  int i = blockIdx.x * 256 + threadIdx.x;
  if (i < N) off[i] += bbase[i >> 8];
  if (i == 0) off[N] = E;
}

__global__ __launch_bounds__(256) void fill_csr(const int* __restrict__ src,
                                                const int* __restrict__ dst,
                                                const int* __restrict__ off,
                                                int* __restrict__ cur,
                                                int* __restrict__ cols, int E) {
  int e = blockIdx.x * 256 + threadIdx.x;
  if (e >= E) return;
  int d = dst[e];
  int p = off[d] + atomicAdd(&cur[d], 1);
  cols[p] = src[e];
}

// ---------------------------------------------------------------------------
// GEMM: Y[m][c] = dinv[m] * dot(X[m][0:128], W[c][0:128])
// Tile: 64 nodes x 64 channels per chunk; 256 threads; thread = 4 nodes x 4 ch.
// LDS: X tile + W chunk, XOR-swizzled at float4 granularity to keep both the
// staging writes and the compute reads bank-conflict-free. 64 KB -> 2 blk/CU.
// ---------------------------------------------------------------------------
template <int OUTC>
__global__ __launch_bounds__(256) void gemm_xw_scale(const float* __restrict__ X,
                                                     const float* __restrict__ W,
                                                     const float* __restrict__ dinv,
                                                     float* __restrict__ Y, int M) {
  __shared__ float4 Xs[64 * 32];
  __shared__ float4 Ws[64 * 32];
  const int tid = threadIdx.x;
  const int m_base = blockIdx.x * 64;

  // stage X tile (64 rows x 128 f32 = 2048 float4), coalesced
  for (int i = tid; i < 64 * 32; i += 256) {
    int r = i >> 5, c4 = i & 31;
    int m = m_base + r;
    float4 v = make_float4(0.f, 0.f, 0.f, 0.f);
    if (m < M) v = ((const float4*)(X + (size_t)m * 128))[c4];
    Xs[(r << 5) + (c4 ^ ((r >> 2) & 7))] = v;
  }

  const int cg = tid & 15;   // channel group: 4 channels
  const int mg = tid >> 4;   // node group: 4 nodes

  for (int cc = 0; cc < OUTC; cc += 64) {
    __syncthreads();  // Xs staged / previous Ws consumed
    for (int i = tid; i < 64 * 32; i += 256) {
      int r = i >> 5, c4 = i & 31;
      float4 v = ((const float4*)(W + (size_t)(cc + r) * 128))[c4];
      Ws[(r << 5) + (c4 ^ ((r >> 2) & 7))] = v;
    }
    __syncthreads();

    float acc[4][4] = {};
#pragma unroll 4
    for (int k4 = 0; k4 < 32; ++k4) {
      float4 xv[4], wv[4];
#pragma unroll
      for (int i = 0; i < 4; ++i)
        xv[i] = Xs[((mg * 4 + i) << 5) + (k4 ^ (mg & 7))];
#pragma unroll
      for (int j = 0; j < 4; ++j)
        wv[j] = Ws[((cg * 4 + j) << 5) + (k4 ^ (cg & 7))];
#pragma unroll
      for (int i = 0; i < 4; ++i)
#pragma unroll
        for (int j = 0; j < 4; ++j)
          acc[i][j] += xv[i].x * wv[j].x + xv[i].y * wv[j].y +
                       xv[i].z * wv[j].z + xv[i].w * wv[j].w;
    }

#pragma unroll
    for (int i = 0; i < 4; ++i) {
      int m = m_base + mg * 4 + i;
      if (m < M) {
        float s = dinv[m];
        float4 o;
        o.x = acc[i][0] * s;
        o.y = acc[i][1] * s;
        o.z = acc[i][2] * s;
        o.w = acc[i][3] * s;
        *(float4*)(Y + (size_t)m * OUTC + cc + cg * 4) = o;
      }
    }
  }
}

// ---------------------------------------------------------------------------
// Aggregation: one wave per destination node. lane holds C/64 channels.
// out[d] = dinv[d]*(xs[d] + sum_e xs[cols[e]]) + bias  (+ReLU)
// Edge column indices broadcast via __shfl; 4 gathers kept in flight.
// ---------------------------------------------------------------------------
template <int C, bool RELU>
__global__ __launch_bounds__(256) void aggregate(const float* __restrict__ xs,
                                                 const int* __restrict__ off,
                                                 const int* __restrict__ cols,
                                                 const float* __restrict__ dinv,
                                                 const float* __restrict__ bias,
                                                 float* __restrict__ out, int N) {
  constexpr int V = C / 64;
  int wid = (int)((blockIdx.x * blockDim.x + threadIdx.x) >> 6);
  int lane = threadIdx.x & 63;
  if (wid >= N) return;

  float a0, a1 = 0.f;
  if constexpr (V == 2) {
    float2 t = *(const float2*)(xs + (size_t)wid * C + lane * 2);
    a0 = t.x;
    a1 = t.y;
  } else {
    a0 = xs[(size_t)wid * C + lane];
  }

  int e1 = off[wid + 1];
  int ebase = off[wid];
  while (ebase < e1) {
    int cnt = e1 - ebase;
    if (cnt > 64) cnt = 64;
    int col = (lane < cnt) ? cols[ebase + lane] : 0;
    int j = 0;
    for (; j + 4 <= cnt; j += 4) {
      int s0 = __shfl(col, j), s1 = __shfl(col, j + 1);
      int s2 = __shfl(col, j + 2), s3 = __shfl(col, j + 3);
      if constexpr (V == 2) {
        float2 t0 = *(const float2*)(xs + (size_t)s0 * C + lane * 2);
        float2 t1 = *(const float2*)(xs + (size_t)s1 * C + lane * 2);
        float2 t2 = *(const float2*)(xs + (size_t)s2 * C + lane * 2);
        float2 t3 = *(const float2*)(xs + (size_t)s3 * C + lane * 2);
        a0 += (t0.x + t1.x) + (t2.x + t3.x);
        a1 += (t0.y + t1.y) + (t2.y + t3.y);
      } else {
        float t0 = xs[(size_t)s0 * C + lane];
        float t1 = xs[(size_t)s1 * C + lane];
        float t2 = xs[(size_t)s2 * C + lane];
        float t3 = xs[(size_t)s3 * C + lane];
        a0 += (t0 + t1) + (t2 + t3);
      }
    }
    for (; j < cnt; ++j) {
      int s = __shfl(col, j);
      if constexpr (V == 2) {
        float2 t = *(const float2*)(xs + (size_t)s * C + lane * 2);
        a0 += t.x;
        a1 += t.y;
      } else {
        a0 += xs[(size_t)s * C + lane];
      }
    }
    ebase += cnt;
  }

  float dd = dinv[wid];
  if constexpr (V == 2) {
    float o0 = a0 * dd + bias[lane * 2];
    float o1 = a1 * dd + bias[lane * 2 + 1];
    if (RELU) {
      o0 = fmaxf(o0, 0.f);
      o1 = fmaxf(o1, 0.f);
    }
    *(float2*)(out + (size_t)wid * C + lane * 2) = make_float2(o0, o1);
  } else {
    float o0 = a0 * dd + bias[lane];
    if (RELU) o0 = fmaxf(o0, 0.f);
    out[(size_t)wid * C + lane] = o0;
  }
}

// ---------------------------------------------------------------------------

extern "C" void kernel_launch(void* const* d_in, const int* in_sizes, int n_in,
                              void* d_out, int out_size, void* d_ws, size_t ws_size,
                              hipStream_t stream) {
  const float* x  = (const float*)d_in[0];
  const int*   ei = (const int*)d_in[1];
  const float* W1 = (const float*)d_in[2];
  const float* b1 = (const float*)d_in[3];
  const float* W2 = (const float*)d_in[4];
  const float* b2 = (const float*)d_in[5];
  const float* W3 = (const float*)d_in[6];
  const float* b3 = (const float*)d_in[7];

  const int N = in_sizes[0] / 128;
  const int E = in_sizes[1] / 2;
  const int* src = ei;
  const int* dst = ei + E;

  // workspace carve-up (ws re-poisoned every call -> rebuild everything)
  char* w = (char*)d_ws;
  size_t p = 0;
  auto alloc = [&](size_t bytes) -> void* {
    void* r = w + p;
    p = (p + bytes + 255) & ~(size_t)255;
    return r;
  };
  float* dinv  = (float*)alloc((size_t)N * 4);
  int*   off   = (int*)alloc((size_t)(N + 1) * 4);
  int*   cnt   = (int*)alloc((size_t)N * 4);
  int*   cur   = (int*)alloc((size_t)N * 4);
  int*   bsum  = (int*)alloc(512 * 4);
  int*   bbase = (int*)alloc(512 * 4);
  int*   cols  = (int*)alloc((size_t)E * 4);
  float* bufA  = (float*)alloc((size_t)N * 128 * 4);
  float* bufB  = (float*)alloc((size_t)N * 128 * 4);

  const int nb = (N + 255) / 256;  // 391 <= 512, fits scan_top
  hipMemsetAsync(cnt, 0, (size_t)N * 4, stream);
  hipMemsetAsync(cur, 0, (size_t)N * 4, stream);
  count_deg<<<(E + 255) / 256, 256, 0, stream>>>(dst, cnt, E);
  make_dinv<<<nb, 256, 0, stream>>>(cnt, dinv, N);
  scan_block<<<nb, 256, 0, stream>>>(cnt, off, bsum, N);
  scan_top<<<1, 512, 0, stream>>>(bsum, bbase, nb);
  scan_add<<<nb, 256, 0, stream>>>(off, bbase, N, E);
  fill_csr<<<(E + 255) / 256, 256, 0, stream>>>(src, dst, off, cur, cols, E);

  const int gb = (N + 63) / 64;
  const int ab = (N + 3) / 4;  // 4 waves (nodes) per 256-thread block

  gemm_xw_scale<128><<<gb, 256, 0, stream>>>(x, W1, dinv, bufA, N);
  aggregate<128, true><<<ab, 256, 0, stream>>>(bufA, off, cols, dinv, b1, bufB, N);
  gemm_xw_scale<128><<<gb, 256, 0, stream>>>(bufB, W2, dinv, bufA, N);
  aggregate<128, true><<<ab, 256, 0, stream>>>(bufA, off, cols, dinv, b2, bufB, N);
  gemm_xw_scale<64><<<gb, 256, 0, stream>>>(bufB, W3, dinv, bufA, N);
  aggregate<64, false><<<ab, 256, 0, stream>>>(bufA, off, cols, dinv, b3,
                                               (float*)d_out, N);
}